// Round 5
// baseline (2802.543 us; speedup 1.0000x reference)
//
#include <hip/hip_runtime.h>
#include <float.h>

// CloudNet (PointNet++-ish) full pipeline on MI355X.
// Correctness contract: FPS + radius selection must be bit-exact vs numpy f32
// (no FMA contraction -> explicit __f*_rn ops; argmax/top_k tie-breaks by
// lowest index). MLP math is free to use pk-FMA (tolerance absorbs rounding).

typedef float f32x2 __attribute__((ext_vector_type(2)));

__device__ __forceinline__ float d2_rn(float ax, float ay, float az,
                                       float bx, float by, float bz) {
  float dx = __fsub_rn(ax, bx), dy = __fsub_rn(ay, by), dz = __fsub_rn(az, bz);
  return __fadd_rn(__fadd_rn(__fmul_rn(dx, dx), __fmul_rn(dy, dy)), __fmul_rn(dz, dz));
}

// u64 max step over a DPP lane pattern (LLVM AMDGPUAtomicOptimizer sequence).
template<int CTRL>
__device__ __forceinline__ unsigned long long dppmax(unsigned long long a) {
  const unsigned int lo = (unsigned int)a, hi = (unsigned int)(a >> 32);
  const unsigned int slo =
      (unsigned int)__builtin_amdgcn_update_dpp(0, (int)lo, CTRL, 0xf, 0xf, true);
  const unsigned int shi =
      (unsigned int)__builtin_amdgcn_update_dpp(0, (int)hi, CTRL, 0xf, 0xf, true);
  const unsigned long long s = ((unsigned long long)shi << 32) | slo;
  return s > a ? s : a;
}

// ---------------- FPS v4: 8 waves, no global stores in loop -----------------
// Key = (f32_bits(mind) << 32) | (N-1-idx): max-key == argmax with numpy's
// lowest-index tie-break (d2 >= 0 so float bits are order-isomorphic).
template<int N, int NS, int T>
__global__ __launch_bounds__(T) void fps_kernel(const float* __restrict__ pos,
                                                float* __restrict__ posq) {
  constexpr int P = N / T;
  constexpr int W = T / 64;
  __shared__ float4 s_xyz[N];
  __shared__ unsigned long long s_red[2][W];
  __shared__ int s_idx[NS];
  const int t = threadIdx.x, b = blockIdx.x;
  const float* pb = pos + (size_t)b * N * 3;
  for (int i = t; i < N; i += T)
    s_xyz[i] = make_float4(pb[i*3+0], pb[i*3+1], pb[i*3+2], 0.f);
  if (t == 0) s_idx[0] = 0;       // deterministic start at point 0
  __syncthreads();
  float px[P], py[P], pz[P], mind[P];
  unsigned int kc[P];
#pragma unroll
  for (int j = 0; j < P; ++j) {
    const float4 c = s_xyz[j*T + t];
    px[j] = c.x; py[j] = c.y; pz[j] = c.z;
    mind[j] = FLT_MAX;            // ref inits to finfo(f32).max
    kc[j] = (unsigned int)(N - 1 - (j*T + t));
  }
  float lx = s_xyz[0].x, ly = s_xyz[0].y, lz = s_xyz[0].z;
  for (int it = 1; it < NS; ++it) {
    float bv = -1.0f; unsigned int bk = 0;
#pragma unroll
    for (int j = 0; j < P; ++j) {
      const float dx = __fsub_rn(px[j], lx);
      const float dy = __fsub_rn(py[j], ly);
      const float dz = __fsub_rn(pz[j], lz);
      const float d = __fadd_rn(__fadd_rn(__fmul_rn(dx, dx), __fmul_rn(dy, dy)),
                                __fmul_rn(dz, dz));
      const float m = fminf(mind[j], d);
      mind[j] = m;
      const bool gt = m > bv;     // strict > => lowest j (= lowest idx) wins
      bv = gt ? m : bv;
      bk = gt ? kc[j] : bk;
    }
    unsigned long long key =
        ((unsigned long long)__float_as_uint(bv) << 32) | bk;
    key = dppmax<0x111>(key);  // row_shr:1
    key = dppmax<0x112>(key);  // row_shr:2
    key = dppmax<0x114>(key);  // row_shr:4
    key = dppmax<0x118>(key);  // row_shr:8
    key = dppmax<0x142>(key);  // row_bcast:15
    key = dppmax<0x143>(key);  // row_bcast:31  -> lane 63 holds wave max
    const int par = it & 1;
    if ((t & 63) == 63) s_red[par][t >> 6] = key;
    __syncthreads();
    unsigned long long v[W];
#pragma unroll
    for (int w = 0; w < W; ++w) v[w] = s_red[par][w];
#pragma unroll
    for (int s2 = W/2; s2 > 0; s2 >>= 1)
#pragma unroll
      for (int w = 0; w < s2; ++w) v[w] = v[w] >= v[w+s2] ? v[w] : v[w+s2];
    const unsigned long long best = v[0];
    const int idx = (N - 1) - (int)(unsigned int)(best & 0xFFFFFFFFull);
    if (t == 0) s_idx[it] = idx;
    const float4 c = s_xyz[idx];        // single b128 broadcast
    lx = c.x; ly = c.y; lz = c.z;
  }
  __syncthreads();
  float* outp = posq + (size_t)b * NS * 3;
  for (int s = t; s < NS; s += T) {
    const float4 c = s_xyz[s_idx[s]];
    outp[(size_t)s*3 + 0] = c.x; outp[(size_t)s*3 + 1] = c.y; outp[(size_t)s*3 + 2] = c.z;
  }
}

// ------------- radius-NN: one block per query, rank-select top-64 -----------
template<int CAP>
__global__ __launch_bounds__(128) void radius_kernel(
    const float* __restrict__ pall, const float* __restrict__ pq,
    int N, int M, float r2,
    int* __restrict__ nidx, int* __restrict__ ncnt) {
  const int bm = blockIdx.x;
  const int b = bm / M;
  const int t = threadIdx.x;
  __shared__ float s_d2[CAP];
  __shared__ int   s_id[CAP];
  __shared__ int   s_cnt;
  if (t == 0) s_cnt = 0;
  __syncthreads();
  const float* pb = pall + (size_t)b * N * 3;
  const float qx = pq[(size_t)bm*3], qy = pq[(size_t)bm*3+1], qz = pq[(size_t)bm*3+2];
  for (int i = t; i < N; i += 128) {
    const float d2 = d2_rn(qx, qy, qz, pb[i*3], pb[i*3+1], pb[i*3+2]);
    if (d2 <= r2) {
      const int p = atomicAdd(&s_cnt, 1);
      if (p < CAP) { s_d2[p] = d2; s_id[p] = i; }
    }
  }
  __syncthreads();
  const int cnt = min(s_cnt, CAP);
  int* out = nidx + (size_t)bm * 64;
  if (cnt <= 64) {
    if (t < cnt) out[t] = s_id[t];      // set equality suffices (max-agg)
    if (t == 0) ncnt[bm] = cnt;
  } else {
    // top_k(-d2): smallest d2, ties -> lower index. (d2,idx) lex rank < 64.
    for (int c = t; c < cnt; c += 128) {
      const float dc = s_d2[c]; const int ic = s_id[c];
      int rank = 0;
      for (int jj = 0; jj < cnt; ++jj)
        rank += (s_d2[jj] < dc) || (s_d2[jj] == dc && s_id[jj] < ic);
      if (rank < 64) out[rank] = s_id[c];
    }
    if (t == 0) ncnt[bm] = 64;
  }
}

// --------- conv1: msg=rel(3) -> 64 -> 64 -> 128, masked max, relu -----------
// 2 waves per query: wave g owns a 32/64-channel slice; h shared in LDS.
__global__ __launch_bounds__(128, 4) void conv1_kernel(
    const float* __restrict__ pos, const float* __restrict__ posq,
    const int* __restrict__ nidx, const int* __restrict__ ncnt,
    const float* __restrict__ w1, const float* __restrict__ b1,
    const float* __restrict__ w2, const float* __restrict__ b2,
    const float* __restrict__ w3, const float* __restrict__ b3,
    float* __restrict__ xout) {
  const int bm = blockIdx.x;      // b*2048 + m
  const int b  = bm >> 11;
  const int t  = threadIdx.x;
  const int j  = t & 63;          // lane = neighbor row
  const int g  = __builtin_amdgcn_readfirstlane(t >> 6);  // wave slice id
  __shared__ float s_x[64 * 64];  // h buffer, XOR-swizzled cols
  __shared__ float s_rel[64 * 4];
  __shared__ float s_out[128];
  const int cnt = ncnt[bm];
  float* outp = xout + (size_t)bm * 128;
  if (cnt == 0) { outp[t] = 0.f; return; }
  if (t < 64) {
    const int n = (t < cnt) ? nidx[(size_t)bm*64 + t] : 0;  // finite filler row
    const float* p = pos + ((size_t)(b << 12) + n) * 3;
    const float qx = posq[(size_t)bm*3+0], qy = posq[(size_t)bm*3+1], qz = posq[(size_t)bm*3+2];
    s_rel[t*4+0] = p[0] - qx; s_rel[t*4+1] = p[1] - qy; s_rel[t*4+2] = p[2] - qz;
  }
  __syncthreads();
  const int sw  = (j & 15) << 1;  // even XOR swizzle, keeps f32x2 pairs aligned
  const int row = j * 64;
  const float rx = s_rel[j*4+0], ry = s_rel[j*4+1], rz = s_rel[j*4+2];
  // L1: 3 -> 64 (our 32-ch slice)
  f32x2 acc[16];
  {
    const f32x2* bv = (const f32x2*)(b1 + g*32);
#pragma unroll
    for (int c = 0; c < 16; ++c) acc[c] = bv[c];
  }
#pragma unroll
  for (int kk = 0; kk < 3; ++kk) {
    const float xk = (kk == 0) ? rx : ((kk == 1) ? ry : rz);
    const f32x2 xv = {xk, xk};
    const float4* wr = (const float4*)(w1 + kk*64 + g*32);
#pragma unroll
    for (int c4 = 0; c4 < 8; ++c4) {
      const float4 w = wr[c4];
      acc[c4*2+0] += xv * f32x2{w.x, w.y};
      acc[c4*2+1] += xv * f32x2{w.z, w.w};
    }
  }
#pragma unroll
  for (int c = 0; c < 16; ++c) {
    f32x2 v = acc[c];
    v.x = fmaxf(v.x, 0.f); v.y = fmaxf(v.y, 0.f);
    *(f32x2*)(&s_x[row + ((g*32 + 2*c) ^ sw)]) = v;
  }
  __syncthreads();
  // L2: 64 -> 64 (our 32-ch slice)
  {
    const f32x2* bv = (const f32x2*)(b2 + g*32);
#pragma unroll
    for (int c = 0; c < 16; ++c) acc[c] = bv[c];
  }
#pragma unroll 2
  for (int k = 0; k < 64; ++k) {
    const float hk = s_x[row + (k ^ sw)];
    const f32x2 hv = {hk, hk};
    const float4* wr = (const float4*)(w2 + k*64 + g*32);
#pragma unroll
    for (int c4 = 0; c4 < 8; ++c4) {
      const float4 w = wr[c4];
      acc[c4*2+0] += hv * f32x2{w.x, w.y};
      acc[c4*2+1] += hv * f32x2{w.z, w.w};
    }
  }
  __syncthreads();  // all L2 reads of h1 done
#pragma unroll
  for (int c = 0; c < 16; ++c) {
    f32x2 v = acc[c];
    v.x = fmaxf(v.x, 0.f); v.y = fmaxf(v.y, 0.f);
    *(f32x2*)(&s_x[row + ((g*32 + 2*c) ^ sw)]) = v;
  }
  __syncthreads();
  // L3: 64 -> 128 (our 64-ch slice, 2 passes) + masked col-max butterfly
#pragma unroll 1
  for (int p = 0; p < 2; ++p) {
    f32x2 a[16];
    {
      const f32x2* bv = (const f32x2*)(b3 + g*64 + p*32);
#pragma unroll
      for (int c = 0; c < 16; ++c) a[c] = bv[c];
    }
#pragma unroll 2
    for (int k = 0; k < 64; ++k) {
      const float hk = s_x[row + (k ^ sw)];
      const f32x2 hv = {hk, hk};
      const float4* wr = (const float4*)(w3 + k*128 + g*64 + p*32);
#pragma unroll
      for (int c4 = 0; c4 < 8; ++c4) {
        const float4 w = wr[c4];
        a[c4*2+0] += hv * f32x2{w.x, w.y};
        a[c4*2+1] += hv * f32x2{w.z, w.w};
      }
    }
    if (j >= cnt) {
#pragma unroll
      for (int c = 0; c < 16; ++c) a[c] = f32x2{-1e30f, -1e30f};  // ref NEG
    }
#pragma unroll
    for (int off = 32; off > 0; off >>= 1) {
#pragma unroll
      for (int c = 0; c < 16; ++c) {
        a[c].x = fmaxf(a[c].x, __shfl_xor(a[c].x, off, 64));
        a[c].y = fmaxf(a[c].y, __shfl_xor(a[c].y, off, 64));
      }
    }
    if (j == 0) {
#pragma unroll
      for (int c = 0; c < 16; ++c) *(f32x2*)(&s_out[g*64 + p*32 + 2*c]) = a[c];
    }
  }
  __syncthreads();
  outp[t] = fmaxf(s_out[t], 0.f);
}

// --- conv2: msg=[x1_j(128), rel(3)] -> 128 -> 128 -> 256, masked max, relu --
// 4 waves per query: wave g owns a 32/64-channel slice; h shared in LDS.
__global__ __launch_bounds__(256, 4) void conv2_kernel(
    const float* __restrict__ x1, const float* __restrict__ pos1, const float* __restrict__ pos2,
    const int* __restrict__ nidx, const int* __restrict__ ncnt,
    const float* __restrict__ w1, const float* __restrict__ b1,
    const float* __restrict__ w2, const float* __restrict__ b2,
    const float* __restrict__ w3, const float* __restrict__ b3,
    float* __restrict__ xout) {
  const int bm = blockIdx.x;      // b*512 + m
  const int b  = bm >> 9;
  const int t  = threadIdx.x;
  const int j  = t & 63;          // neighbor row
  const int g  = __builtin_amdgcn_readfirstlane(t >> 6);  // wave slice id
  __shared__ float s_x[64 * 128]; // msg/h buffer, XOR-swizzled cols
  __shared__ float s_rel[64 * 4];
  __shared__ int   s_n[64];
  __shared__ float s_out[256];
  const int cnt = ncnt[bm];
  float* outp = xout + (size_t)bm * 256;
  if (cnt == 0) { outp[t] = 0.f; return; }
  if (t < 64) {
    const int n = (t < cnt) ? nidx[(size_t)bm*64 + t] : 0;  // finite filler row
    s_n[t] = n;
    const float* p = pos1 + ((size_t)(b << 11) + n) * 3;
    const float qx = pos2[(size_t)bm*3+0], qy = pos2[(size_t)bm*3+1], qz = pos2[(size_t)bm*3+2];
    s_rel[t*4+0] = p[0] - qx; s_rel[t*4+1] = p[1] - qy; s_rel[t*4+2] = p[2] - qz;
  }
  __syncthreads();
  // stage x1 rows (gather), swizzled
  for (int i = t; i < 64*128; i += 256) {
    const int r = i >> 7, c = i & 127;
    s_x[r*128 + (c ^ ((r & 15) << 1))] = x1[((size_t)(b << 11) + s_n[r])*128 + c];
  }
  __syncthreads();
  const int sw  = (j & 15) << 1;
  const int row = j * 128;
  // L1: 131 -> 128 (our 32-ch slice)
  f32x2 acc[16];
  {
    const f32x2* bv = (const f32x2*)(b1 + g*32);
#pragma unroll
    for (int c = 0; c < 16; ++c) acc[c] = bv[c];
  }
#pragma unroll 2
  for (int k = 0; k < 128; ++k) {
    const float xk = s_x[row + (k ^ sw)];
    const f32x2 xv = {xk, xk};
    const float4* wr = (const float4*)(w1 + k*128 + g*32);
#pragma unroll
    for (int c4 = 0; c4 < 8; ++c4) {
      const float4 w = wr[c4];
      acc[c4*2+0] += xv * f32x2{w.x, w.y};
      acc[c4*2+1] += xv * f32x2{w.z, w.w};
    }
  }
#pragma unroll
  for (int kk = 0; kk < 3; ++kk) {
    const float xk = s_rel[j*4 + kk];
    const f32x2 xv = {xk, xk};
    const float4* wr = (const float4*)(w1 + (128 + kk)*128 + g*32);
#pragma unroll
    for (int c4 = 0; c4 < 8; ++c4) {
      const float4 w = wr[c4];
      acc[c4*2+0] += xv * f32x2{w.x, w.y};
      acc[c4*2+1] += xv * f32x2{w.z, w.w};
    }
  }
  __syncthreads();  // all L1 reads of msg done
#pragma unroll
  for (int c = 0; c < 16; ++c) {
    f32x2 v = acc[c];
    v.x = fmaxf(v.x, 0.f); v.y = fmaxf(v.y, 0.f);
    *(f32x2*)(&s_x[row + ((g*32 + 2*c) ^ sw)]) = v;
  }
  __syncthreads();
  // L2: 128 -> 128 (our 32-ch slice)
  {
    const f32x2* bv = (const f32x2*)(b2 + g*32);
#pragma unroll
    for (int c = 0; c < 16; ++c) acc[c] = bv[c];
  }
#pragma unroll 2
  for (int k = 0; k < 128; ++k) {
    const float hk = s_x[row + (k ^ sw)];
    const f32x2 hv = {hk, hk};
    const float4* wr = (const float4*)(w2 + k*128 + g*32);
#pragma unroll
    for (int c4 = 0; c4 < 8; ++c4) {
      const float4 w = wr[c4];
      acc[c4*2+0] += hv * f32x2{w.x, w.y};
      acc[c4*2+1] += hv * f32x2{w.z, w.w};
    }
  }
  __syncthreads();  // all L2 reads of h1 done
#pragma unroll
  for (int c = 0; c < 16; ++c) {
    f32x2 v = acc[c];
    v.x = fmaxf(v.x, 0.f); v.y = fmaxf(v.y, 0.f);
    *(f32x2*)(&s_x[row + ((g*32 + 2*c) ^ sw)]) = v;
  }
  __syncthreads();
  // L3: 128 -> 256 (our 64-ch slice, 2 passes) + masked col-max butterfly
#pragma unroll 1
  for (int p = 0; p < 2; ++p) {
    f32x2 a[16];
    {
      const f32x2* bv = (const f32x2*)(b3 + g*64 + p*32);
#pragma unroll
      for (int c = 0; c < 16; ++c) a[c] = bv[c];
    }
#pragma unroll 2
    for (int k = 0; k < 128; ++k) {
      const float hk = s_x[row + (k ^ sw)];
      const f32x2 hv = {hk, hk};
      const float4* wr = (const float4*)(w3 + k*256 + g*64 + p*32);
#pragma unroll
      for (int c4 = 0; c4 < 8; ++c4) {
        const float4 w = wr[c4];
        a[c4*2+0] += hv * f32x2{w.x, w.y};
        a[c4*2+1] += hv * f32x2{w.z, w.w};
      }
    }
    if (j >= cnt) {
#pragma unroll
      for (int c = 0; c < 16; ++c) a[c] = f32x2{-1e30f, -1e30f};  // ref NEG
    }
#pragma unroll
    for (int off = 32; off > 0; off >>= 1) {
#pragma unroll
      for (int c = 0; c < 16; ++c) {
        a[c].x = fmaxf(a[c].x, __shfl_xor(a[c].x, off, 64));
        a[c].y = fmaxf(a[c].y, __shfl_xor(a[c].y, off, 64));
      }
    }
    if (j == 0) {
#pragma unroll
      for (int c = 0; c < 16; ++c) *(f32x2*)(&s_out[g*64 + p*32 + 2*c]) = a[c];
    }
  }
  __syncthreads();
  outp[t] = fmaxf(s_out[t], 0.f);
}

// --------- global MLP 259->256->512->1024, per-block(16pt) partial max ------
__global__ __launch_bounds__(256) void gmlp_kernel(
    const float* __restrict__ x2, const float* __restrict__ pos2,
    const float* __restrict__ w1, const float* __restrict__ b1,
    const float* __restrict__ w2, const float* __restrict__ b2,
    const float* __restrict__ w3, const float* __restrict__ b3,
    float* __restrict__ gpart) {
  const int blk = blockIdx.x;     // 16 points per block (group = 8 blocks)
  const int t = threadIdx.x;
  __shared__ float sA[260 * 18];  // [k][p], pad 18 for 8B alignment
  __shared__ float sB[512 * 18];
  const int p0 = blk * 16;
  for (int i = t; i < 16*256; i += 256) {
    const int p = i >> 8, k = i & 255;
    sA[k*18 + p] = x2[(size_t)(p0 + p)*256 + k];
  }
  if (t < 48) { const int p = t/3, c = t%3; sA[(256+c)*18 + p] = pos2[(size_t)(p0+p)*3 + c]; }
  __syncthreads();
  f32x2 h1[8];
  { const float bb = b1[t];
#pragma unroll
    for (int p8 = 0; p8 < 8; ++p8) h1[p8] = f32x2{bb, bb}; }
#pragma unroll 2
  for (int k = 0; k < 259; ++k) {
    const float w = w1[(size_t)k*256 + t];
    const f32x2 wv = {w, w};
    const f32x2* row = (const f32x2*)(&sA[k*18]);
#pragma unroll
    for (int p8 = 0; p8 < 8; ++p8) h1[p8] += row[p8] * wv;
  }
  __syncthreads();
#pragma unroll
  for (int p8 = 0; p8 < 8; ++p8) {
    f32x2 a = h1[p8];
    a.x = fmaxf(a.x, 0.f); a.y = fmaxf(a.y, 0.f);
    *(f32x2*)(&sA[t*18 + 2*p8]) = a;
  }
  __syncthreads();
  f32x2 h2a[8], h2b[8];
  { const float ba = b2[t], bb = b2[t + 256];
#pragma unroll
    for (int p8 = 0; p8 < 8; ++p8) { h2a[p8] = f32x2{ba, ba}; h2b[p8] = f32x2{bb, bb}; } }
#pragma unroll 2
  for (int k = 0; k < 256; ++k) {
    const float wa = w2[(size_t)k*512 + t];
    const float wb = w2[(size_t)k*512 + t + 256];
    const f32x2 wav = {wa, wa}, wbv = {wb, wb};
    const f32x2* row = (const f32x2*)(&sA[k*18]);
#pragma unroll
    for (int p8 = 0; p8 < 8; ++p8) { const f32x2 x = row[p8]; h2a[p8] += x*wav; h2b[p8] += x*wbv; }
  }
  __syncthreads();
#pragma unroll
  for (int p8 = 0; p8 < 8; ++p8) {
    f32x2 a = h2a[p8], c = h2b[p8];
    a.x = fmaxf(a.x, 0.f); a.y = fmaxf(a.y, 0.f);
    c.x = fmaxf(c.x, 0.f); c.y = fmaxf(c.y, 0.f);
    *(f32x2*)(&sB[t*18 + 2*p8]) = a;
    *(f32x2*)(&sB[(t+256)*18 + 2*p8]) = c;
  }
  __syncthreads();
  f32x2 a3[4][8];
#pragma unroll
  for (int c = 0; c < 4; ++c) {
    const float bb = b3[t + c*256];
#pragma unroll
    for (int p8 = 0; p8 < 8; ++p8) a3[c][p8] = f32x2{bb, bb};
  }
#pragma unroll 2
  for (int k = 0; k < 512; ++k) {
    const f32x2* row = (const f32x2*)(&sB[k*18]);
    f32x2 xk[8];
#pragma unroll
    for (int p8 = 0; p8 < 8; ++p8) xk[p8] = row[p8];
#pragma unroll
    for (int c = 0; c < 4; ++c) {
      const float w = w3[(size_t)k*1024 + t + c*256];
      const f32x2 wv = {w, w};
#pragma unroll
      for (int p8 = 0; p8 < 8; ++p8) a3[c][p8] += xk[p8] * wv;
    }
  }
#pragma unroll
  for (int c = 0; c < 4; ++c) {
    f32x2 m2 = a3[c][0];
#pragma unroll
    for (int p8 = 1; p8 < 8; ++p8) {
      m2.x = fmaxf(m2.x, a3[c][p8].x); m2.y = fmaxf(m2.y, a3[c][p8].y);
    }
    gpart[(size_t)blk*1024 + t + c*256] = fmaxf(m2.x, m2.y);
  }
}

// ------ head MLP: fused 8-row gpart max -> 1024->512->256->7 per row --------
__global__ __launch_bounds__(256) void head_kernel(
    const float* __restrict__ gpart,
    const float* __restrict__ l1w, const float* __restrict__ l1b,
    const float* __restrict__ l2w, const float* __restrict__ l2b,
    const float* __restrict__ l3w, const float* __restrict__ l3b,
    float* __restrict__ h3) {
  const int r = blockIdx.x, t = threadIdx.x;
  __shared__ float sIn[1024];
  __shared__ float sH[512];
  __shared__ float sH2[256];
  for (int i = t; i < 1024; i += 256) {
    float v = gpart[(size_t)(r*8)*1024 + i];
#pragma unroll
    for (int rr = 1; rr < 8; ++rr) v = fmaxf(v, gpart[(size_t)(r*8 + rr)*1024 + i]);
    sIn[i] = v;
  }
  __syncthreads();
  float a0 = l1b[t], a1 = l1b[t + 256];
#pragma unroll 4
  for (int k = 0; k < 1024; ++k) {
    const float x = sIn[k];
    a0 += x * l1w[(size_t)k*512 + t];
    a1 += x * l1w[(size_t)k*512 + t + 256];
  }
  sH[t] = fmaxf(a0, 0.f); sH[t+256] = fmaxf(a1, 0.f);
  __syncthreads();
  float a = l2b[t];
#pragma unroll 4
  for (int k = 0; k < 512; ++k) a += sH[k] * l2w[(size_t)k*256 + t];
  sH2[t] = fmaxf(a, 0.f);
  __syncthreads();
  if (t < 7) {
    float acc = l3b[t];
#pragma unroll 4
    for (int k = 0; k < 256; ++k) acc += sH2[k] * l3w[(size_t)k*7 + t];
    h3[(size_t)r*7 + t] = acc;
  }
}

// ---------------- mean over 4 group-rows + quaternion normalize -------------
__global__ void final_kernel(const float* __restrict__ h3, float* __restrict__ out) {
  const int b = threadIdx.x;
  if (b >= 8) return;
  float v[7];
#pragma unroll
  for (int c = 0; c < 7; ++c) {
    const float s = ((h3[(b*4+0)*7+c] + h3[(b*4+1)*7+c]) + h3[(b*4+2)*7+c]) + h3[(b*4+3)*7+c];
    v[c] = s * 0.25f;
  }
  const float nrm = fmaxf(sqrtf(((v[3]*v[3] + v[4]*v[4]) + v[5]*v[5]) + v[6]*v[6]), 1e-12f);
  out[b*7+0] = v[0]; out[b*7+1] = v[1]; out[b*7+2] = v[2];
  out[b*7+3] = v[3]/nrm; out[b*7+4] = v[4]/nrm;
  out[b*7+5] = v[5]/nrm; out[b*7+6] = v[6]/nrm;
}

extern "C" void kernel_launch(void* const* d_in, const int* in_sizes, int n_in,
                              void* d_out, int out_size, void* d_ws, size_t ws_size,
                              hipStream_t stream) {
  const float* points = (const float*)d_in[0];
  const float* sa1_w1 = (const float*)d_in[1];
  const float* sa1_b1 = (const float*)d_in[2];
  const float* sa1_w2 = (const float*)d_in[3];
  const float* sa1_b2 = (const float*)d_in[4];
  const float* sa1_w3 = (const float*)d_in[5];
  const float* sa1_b3 = (const float*)d_in[6];
  const float* sa2_w1 = (const float*)d_in[7];
  const float* sa2_b1 = (const float*)d_in[8];
  const float* sa2_w2 = (const float*)d_in[9];
  const float* sa2_b2 = (const float*)d_in[10];
  const float* sa2_w3 = (const float*)d_in[11];
  const float* sa2_b3 = (const float*)d_in[12];
  const float* g_w1   = (const float*)d_in[13];
  const float* g_b1   = (const float*)d_in[14];
  const float* g_w2   = (const float*)d_in[15];
  const float* g_b2   = (const float*)d_in[16];
  const float* g_w3   = (const float*)d_in[17];
  const float* g_b3   = (const float*)d_in[18];
  const float* l1_w   = (const float*)d_in[19];
  const float* l1_b   = (const float*)d_in[20];
  const float* l2_w   = (const float*)d_in[21];
  const float* l2_b   = (const float*)d_in[22];
  const float* l3_w   = (const float*)d_in[23];
  const float* l3_b   = (const float*)d_in[24];

  // Workspace carve-up (all 4-byte elements), ~19.3 MB total.
  float* ws = (float*)d_ws;
  size_t o = 0;
  float* pos1  = ws + o; o += (size_t)8*2048*3;
  float* pos2  = ws + o; o += (size_t)8*512*3;
  int*   nidx1 = (int*)(ws + o); o += (size_t)8*2048*64;
  int*   ncnt1 = (int*)(ws + o); o += (size_t)8*2048;
  int*   nidx2 = (int*)(ws + o); o += (size_t)8*512*64;
  int*   ncnt2 = (int*)(ws + o); o += (size_t)8*512;
  float* x1    = ws + o; o += (size_t)8*2048*128;
  float* x2    = ws + o; o += (size_t)8*512*256;
  float* gpart = ws + o; o += (size_t)256*1024;
  float* gmaxb = ws + o; o += (size_t)32*1024;  // (unused since head fuses gmax)
  float* h3    = ws + o; o += (size_t)32*7;
  (void)gmaxb;

  // Radius thresholds: Python computes r*r in double, JAX weak-types to f32.
  const float R2_1 = (float)(0.1 * 0.1);
  const float R2_2 = (float)(0.2 * 0.2);

  fps_kernel<4096, 2048, 512><<<8, 512, 0, stream>>>(points, pos1);
  radius_kernel<1024><<<8*2048, 128, 0, stream>>>(points, pos1, 4096, 2048, R2_1, nidx1, ncnt1);
  conv1_kernel<<<8*2048, 128, 0, stream>>>(points, pos1, nidx1, ncnt1,
                                           sa1_w1, sa1_b1, sa1_w2, sa1_b2, sa1_w3, sa1_b3, x1);
  fps_kernel<2048, 512, 512><<<8, 512, 0, stream>>>(pos1, pos2);
  radius_kernel<1024><<<8*512, 128, 0, stream>>>(pos1, pos2, 2048, 512, R2_2, nidx2, ncnt2);
  conv2_kernel<<<8*512, 256, 0, stream>>>(x1, pos1, pos2, nidx2, ncnt2,
                                          sa2_w1, sa2_b1, sa2_w2, sa2_b2, sa2_w3, sa2_b3, x2);
  gmlp_kernel<<<256, 256, 0, stream>>>(x2, pos2, g_w1, g_b1, g_w2, g_b2, g_w3, g_b3, gpart);
  head_kernel<<<32, 256, 0, stream>>>(gpart, l1_w, l1_b, l2_w, l2_b, l3_w, l3_b, h3);
  final_kernel<<<1, 64, 0, stream>>>(h3, (float*)d_out);
}